// Round 11
// baseline (203.178 us; speedup 1.0000x reference)
//
#include <hip/hip_runtime.h>
#include <hip/hip_bf16.h>

typedef __attribute__((ext_vector_type(8))) __bf16 bf16x8;
typedef __attribute__((ext_vector_type(8))) short short8;
typedef __attribute__((ext_vector_type(4))) float f32x4;
typedef __attribute__((ext_vector_type(16))) float f32x16;
typedef __attribute__((ext_vector_type(4))) short sh4;

typedef __attribute__((address_space(1))) void GVoid;
typedef __attribute__((address_space(3))) void LVoid;

#define NEGBIG (-1e30f)
#define SCL 0.18033688011112042f   // 0.125 * log2(e): folded into Q at GEMM1 epilogue

constexpr int TT = 2048, CC = 1024, HH = 16, DD = 64, C3 = 3072;

__device__ __forceinline__ unsigned short f2bf(float f) {   // RNE
  unsigned int i = __float_as_uint(f);
  return (unsigned short)((i + 0x7FFFu + ((i >> 16) & 1u)) >> 16);
}
__device__ __forceinline__ void async16(const void* g, void* l) {
  __builtin_amdgcn_global_load_lds((GVoid*)g, (LVoid*)l, 16, 0, 0);
}

// ---------- pre-pass: fp32 -> bf16 elementwise convert ----------
__global__ __launch_bounds__(256) void cvt_bf16(
    const float* __restrict__ in, unsigned short* __restrict__ out, int n8)
{
  const int i = blockIdx.x * 256 + threadIdx.x;
  if (i >= n8) return;
  const float* p = in + (size_t)i * 8;
  f32x4 a = *(const f32x4*)p, b = *(const f32x4*)(p + 4);
  sh4 r0, r1;
  ((unsigned short*)&r0)[0] = f2bf(a[0]); ((unsigned short*)&r0)[1] = f2bf(a[1]);
  ((unsigned short*)&r0)[2] = f2bf(a[2]); ((unsigned short*)&r0)[3] = f2bf(a[3]);
  ((unsigned short*)&r1)[0] = f2bf(b[0]); ((unsigned short*)&r1)[1] = f2bf(b[1]);
  ((unsigned short*)&r1)[2] = f2bf(b[2]); ((unsigned short*)&r1)[3] = f2bf(b[3]);
  *(sh4*)(out + (size_t)i * 8) = r0;
  *(sh4*)(out + (size_t)i * 8 + 4) = r1;
}

// ---------- pre-pass: transpose + convert: fp32 in[R][Cd] -> bf16 out[Cd][R] ----------
__global__ __launch_bounds__(256) void transpose_cvt(
    const float* __restrict__ in, unsigned short* __restrict__ out, int R, int Cd)
{
  __shared__ __align__(16) unsigned short tile[64 * 72];
  const int r0 = blockIdx.y * 64, c0 = blockIdx.x * 64;
  const int tid = threadIdx.x;
#pragma unroll
  for (int r = 0; r < 2; ++r) {
    const int elem = r * 2048 + tid * 8;
    const int ii = elem >> 6, jj = elem & 63;
    const float* p = in + (size_t)(r0 + ii) * Cd + c0 + jj;
    f32x4 a = *(const f32x4*)p, b = *(const f32x4*)(p + 4);
    short8 v;
    ((unsigned short*)&v)[0] = f2bf(a[0]); ((unsigned short*)&v)[1] = f2bf(a[1]);
    ((unsigned short*)&v)[2] = f2bf(a[2]); ((unsigned short*)&v)[3] = f2bf(a[3]);
    ((unsigned short*)&v)[4] = f2bf(b[0]); ((unsigned short*)&v)[5] = f2bf(b[1]);
    ((unsigned short*)&v)[6] = f2bf(b[2]); ((unsigned short*)&v)[7] = f2bf(b[3]);
    *(short8*)&tile[ii * 72 + jj] = v;
  }
  __syncthreads();
#pragma unroll
  for (int r = 0; r < 2; ++r) {
    const int elem = r * 2048 + tid * 8;
    const int jj = elem >> 6, ii0 = elem & 63;
    short8 v;
#pragma unroll
    for (int e = 0; e < 8; ++e) ((unsigned short*)&v)[e] = tile[(ii0 + e) * 72 + jj];
    *(short8*)&out[(size_t)(c0 + jj) * R + r0 + ii0] = v;
  }
}

// ---------------- GEMM, 128x128 tile, single-barrier double-buffered ----------------
// + XCD column-slab swizzle (T1): 768 blocks = 96/XCD exactly; each XCD owns 3
// B-panel columns (768 KB -> L2-resident) instead of thrashing all 6 MB of B.
// MODE 0 (QKV): gn<1024 -> Q*SCL bf16; 1024..2047 -> K bf16; >=2048 -> Vt packed.
template <int MODE>
__global__ __launch_bounds__(256) void gemm_bt(
    const unsigned short* __restrict__ A,
    const unsigned short* __restrict__ Bt,
    const float* __restrict__ bias,
    void* __restrict__ Cp, unsigned short* __restrict__ Vt,
    int M, int N, int K, int lda)
{
  __shared__ __align__(16) unsigned short sA[2][128 * 32];
  __shared__ __align__(16) unsigned short sB[2][128 * 32];
  const int tid = threadIdx.x;
  const int w = tid >> 6, l = tid & 63, ln = l & 15, quad = l >> 4;
  const int wm = w >> 1, wn = w & 1;
  // XCD swizzle: lid -> XCD k owns contiguous chunk, column-major within chunk
  const int lid = blockIdx.y * gridDim.x + blockIdx.x;
  const int per = (gridDim.x * gridDim.y) >> 3;       // blocks per XCD (grid % 8 == 0)
  const int swz = (lid & 7) * per + (lid >> 3);
  const int bx = swz / gridDim.y, by = swz % gridDim.y;
  const int m0 = by * 128, n0 = bx * 128;
  f32x4 acc[4][4] = {};

  const int elem0 = tid * 8;                 // staging coords (constant per thread)
  const int ar0 = elem0 >> 5, ac0 = elem0 & 31;
  const int ar1 = (2048 + elem0) >> 5, ac1 = ac0;

  // prologue: stage k0=0 into buf 0
  async16(A  + (size_t)(m0 + ar0) * lda + ac0, &sA[0][w * 512]);
  async16(Bt + (size_t)(n0 + ar0) * K   + ac0, &sB[0][w * 512]);
  async16(A  + (size_t)(m0 + ar1) * lda + ac1, &sA[0][2048 + w * 512]);
  async16(Bt + (size_t)(n0 + ar1) * K   + ac1, &sB[0][2048 + w * 512]);
  __syncthreads();                           // implicit vmcnt(0) drain: buf0 ready

  int buf = 0;
  for (int k0 = 0; k0 < K; k0 += 32, buf ^= 1) {
    if (k0 + 32 < K) {                       // stage NEXT tile into other buffer
      const int nb = buf ^ 1, kn = k0 + 32;
      async16(A  + (size_t)(m0 + ar0) * lda + kn + ac0, &sA[nb][w * 512]);
      async16(Bt + (size_t)(n0 + ar0) * K   + kn + ac0, &sB[nb][w * 512]);
      async16(A  + (size_t)(m0 + ar1) * lda + kn + ac1, &sA[nb][2048 + w * 512]);
      async16(Bt + (size_t)(n0 + ar1) * K   + kn + ac1, &sB[nb][2048 + w * 512]);
    }

    bf16x8 af[4], bfr[4];
#pragma unroll
    for (int i = 0; i < 4; i++)
      af[i] = *(const bf16x8*)&sA[buf][(wm * 64 + i * 16 + ln) * 32 + quad * 8];
#pragma unroll
    for (int j = 0; j < 4; j++)
      bfr[j] = *(const bf16x8*)&sB[buf][(wn * 64 + j * 16 + ln) * 32 + quad * 8];
#pragma unroll
    for (int i = 0; i < 4; i++)
#pragma unroll
      for (int j = 0; j < 4; j++)
        acc[i][j] = __builtin_amdgcn_mfma_f32_16x16x32_bf16(af[i], bfr[j], acc[i][j], 0, 0, 0);

    __syncthreads();                         // one barrier/K-step
  }

  float bj[4];
#pragma unroll
  for (int j = 0; j < 4; j++) bj[j] = bias[n0 + wn * 64 + j * 16 + ln];

#pragma unroll
  for (int i = 0; i < 4; i++) {
#pragma unroll
    for (int j = 0; j < 4; j++) {
      const int gn = n0 + wn * 64 + j * 16 + ln;
      if (MODE == 0 && gn >= 2048) {                 // V: pack g-quad -> one 8B store
        const int hh = (gn >> 6) & 15, dd = gn & 63;
        const int gm0 = m0 + wm * 64 + i * 16 + quad * 4;
        const int bb = gm0 >> 11, t0 = gm0 & 2047;   // g-quad never crosses batch
        sh4 rv;
#pragma unroll
        for (int g = 0; g < 4; ++g)
          ((unsigned short*)&rv)[g] = f2bf(acc[i][j][g] + bj[j]);
        *(sh4*)&Vt[((size_t)((bb * HH + hh) * DD + dd)) * TT + t0] = rv;
      } else {
#pragma unroll
        for (int g = 0; g < 4; ++g) {
          const int gm = m0 + wm * 64 + i * 16 + quad * 4 + g;
          float v = acc[i][j][g] + bj[j];
          if (MODE == 0) {
            if (gn < 1024) v *= SCL;   // fold softmax scale into Q (pre-round: free)
            ((unsigned short*)Cp)[(size_t)gm * 2048 + gn] = f2bf(v);
          } else {
            ((float*)Cp)[(size_t)gm * N + gn] = v;
          }
        }
      }
    }
  }
}

// ---------------- GEMM, 128x64 tile (proj), dbuf + XCD swizzle ----------------
__global__ __launch_bounds__(256) void gemm_n64(
    const unsigned short* __restrict__ A,
    const unsigned short* __restrict__ Bt,
    const float* __restrict__ bias,
    float* __restrict__ Cp, int M, int N, int K, int lda)
{
  __shared__ __align__(16) unsigned short sA[2][128 * 32];
  __shared__ __align__(16) unsigned short sB[2][64 * 32];
  const int tid = threadIdx.x;
  const int w = tid >> 6, l = tid & 63, ln = l & 15, quad = l >> 4;
  const int wm = w >> 1, wn = w & 1;
  const int lid = blockIdx.y * gridDim.x + blockIdx.x;
  const int per = (gridDim.x * gridDim.y) >> 3;
  const int swz = (lid & 7) * per + (lid >> 3);
  const int bx = swz / gridDim.y, by = swz % gridDim.y;
  const int m0 = by * 128, n0 = bx * 64;
  f32x4 acc[4][2] = {};

  const int elem0 = tid * 8;
  const int ar0 = elem0 >> 5, ac0 = elem0 & 31;
  const int ar1 = (2048 + elem0) >> 5, ac1 = ac0;

  async16(A  + (size_t)(m0 + ar0) * lda + ac0, &sA[0][w * 512]);
  async16(A  + (size_t)(m0 + ar1) * lda + ac1, &sA[0][2048 + w * 512]);
  async16(Bt + (size_t)(n0 + ar0) * K   + ac0, &sB[0][w * 512]);
  __syncthreads();

  int buf = 0;
  for (int k0 = 0; k0 < K; k0 += 32, buf ^= 1) {
    if (k0 + 32 < K) {
      const int nb = buf ^ 1, kn = k0 + 32;
      async16(A  + (size_t)(m0 + ar0) * lda + kn + ac0, &sA[nb][w * 512]);
      async16(A  + (size_t)(m0 + ar1) * lda + kn + ac1, &sA[nb][2048 + w * 512]);
      async16(Bt + (size_t)(n0 + ar0) * K   + kn + ac0, &sB[nb][w * 512]);
    }

    bf16x8 af[4], bfr[2];
#pragma unroll
    for (int i = 0; i < 4; i++)
      af[i] = *(const bf16x8*)&sA[buf][(wm * 64 + i * 16 + ln) * 32 + quad * 8];
#pragma unroll
    for (int j = 0; j < 2; j++)
      bfr[j] = *(const bf16x8*)&sB[buf][(wn * 32 + j * 16 + ln) * 32 + quad * 8];
#pragma unroll
    for (int i = 0; i < 4; i++)
#pragma unroll
      for (int j = 0; j < 2; j++)
        acc[i][j] = __builtin_amdgcn_mfma_f32_16x16x32_bf16(af[i], bfr[j], acc[i][j], 0, 0, 0);

    __syncthreads();
  }

  float bj[2];
#pragma unroll
  for (int j = 0; j < 2; j++) bj[j] = bias[n0 + wn * 32 + j * 16 + ln];

#pragma unroll
  for (int i = 0; i < 4; i++)
#pragma unroll
    for (int g = 0; g < 4; ++g) {
      const int gm = m0 + wm * 64 + i * 16 + quad * 4 + g;
#pragma unroll
      for (int j = 0; j < 2; j++) {
        const int gn = n0 + wn * 32 + j * 16 + ln;
        Cp[(size_t)gm * N + gn] = acc[i][j][g] + bj[j];
      }
    }
}

// ---------------- Flash attention (causal), D=64, FOUR parity groups ----------------
// Round-8 theory: the only lever that has moved attn is waves/SIMD with INDEPENDENT
// work (r7: 1->2 waves/SIMD = -12us). This kernel: 1024 thr = 16 waves = 4 waves/SIMD,
// one block/CU. FOUR k-parity groups (kb === grp mod 4) of 4 row-waves each, all
// running the verified attn32q math (32x32 S^T MFMA, in-register cvt_pk/permlane
// softmax, raw v_exp_f32). PV is SAME-SLOT (no lag: no LDS room for triple-buffer;
// 4-way TLP replaces intra-wave ILP). Slots per {p,15-p} pair = 9 (vs 17): half the
// barriers, double the TLP. LDS 144 KB = kt[4][2]+vt[4][2]; the 4-way O/l merge
// OVERLAYS the dead kt/vt space after the loop. VGPR must stay <=128 for 16 waves/CU
// (launch_bounds(1024,1); attn32q measured 124 with MORE liveness from PV-lag).
__global__ __launch_bounds__(1024, 1) void attn4g(
    unsigned short* __restrict__ QK, const unsigned short* __restrict__ Vt)
{
  __shared__ __align__(16) unsigned short smem[73728];      // 144 KB
  // layout: kt(grp,buf) = smem + (grp*2+buf)*4608 ; vt(grp,buf) = +36864 same idx
  const int pair = blockIdx.x, bh = blockIdx.y;
  const int b = bh >> 4, h = bh & 15;
  const int tid = threadIdx.x;
  const int wid = tid >> 6, grp = wid >> 2, wg = wid & 3, l = tid & 63;
  const int c = l & 31, h2 = l >> 5;
  const int gtid = tid & 255;                               // within group (4 waves)
  unsigned short*       Qp = QK + (size_t)b * TT * 2048 + h * DD;
  const unsigned short* Kp = QK + (size_t)b * TT * 2048 + CC + h * DD;
  const unsigned short* Vh = Vt + (size_t)bh * DD * TT;
  const int si0 = gtid >> 3, so = (gtid & 7) * 8;           // group stages 64x64 in 2 passes
  unsigned short* kt0 = smem + grp * 2 * 4608;              // + ck*4608
  unsigned short* vt0 = smem + 36864 + grp * 2 * 4608;
  float* Ms  = (float*)smem;                                // [(grp-1)*4+wg][32][64] overlay
  float* Lxp = (float*)smem + 24576;                        // [(grp-1)*4+wg][64] overlay

  for (int ph = 0; ph < 2; ++ph) {
    const int qt = ph ? 15 - pair : pair;
    const int qbase = qt * 128 + wg * 32;                   // wave's first q-row
    const int qm = qbase + c - 4 * h2;                      // mask helper (verified)
    bf16x8 qv[4];
#pragma unroll
    for (int ds = 0; ds < 4; ++ds)                          // Q B-operand frags
      qv[ds] = *(const bf16x8*)&Qp[(size_t)(qbase + c) * 2048 + ds * 16 + h2 * 8];

    f32x16 oacc[2] = {};
    float lsum = 0.0f;
    const int kbmax = 2 * qt + 1;
    const int nslot = (qt + 2) >> 1;                        // ceil((2qt+2)/4)

    __syncthreads();                                        // prior phase merge-reads done
    if (grp <= kbmax) {                                     // stage kb=grp -> buf 0
#pragma unroll
      for (int r = 0; r < 2; ++r) {
        const int si = si0 + 32 * r;
        *(short8*)&kt0[si * 72 + so] = *(const short8*)&Kp[(size_t)(grp * 64 + si) * 2048 + so];
        *(short8*)&vt0[si * 72 + so] = *(const short8*)&Vh[(size_t)si * TT + grp * 64 + so];
      }
    }
    __syncthreads();                                        // buf0 visible

    for (int slot = 0; slot < nslot; ++slot) {
      const int kb = 4 * slot + grp;
      const int ck = slot & 1;
      const bool pref = (kb + 4 <= kbmax);                  // group active next slot
      short8 pk[2], pv[2];
      if (pref) {                                           // prefetch kb+4 -> regs
#pragma unroll
        for (int r = 0; r < 2; ++r) {
          const int si = si0 + 32 * r;
          pk[r] = *(const short8*)&Kp[(size_t)((kb + 4) * 64 + si) * 2048 + so];
          pv[r] = *(const short8*)&Vh[(size_t)si * TT + (kb + 4) * 64 + so];
        }
      }
      const bool act = (kb * 64 <= qbase + 31);             // wave-uniform; implies kb<=kbmax
      if (act) {
        f32x16 sacc[2];
#pragma unroll
        for (int kg = 0; kg < 2; ++kg) {                    // S^T(kb) = K * Q^T
          f32x16 sa = {};
#pragma unroll
          for (int ds = 0; ds < 4; ++ds) {
            bf16x8 kf = *(const bf16x8*)&kt0[ck * 4608 + (kg * 32 + c) * 72 + ds * 16 + h2 * 8];
            sa = __builtin_amdgcn_mfma_f32_32x32x16_bf16(kf, qv[ds], sa, 0, 0, 0);
          }
          sacc[kg] = sa;
        }
        const bool need_mask = (kb * 64 + 63 > qbase);      // diagonal tiles only
        float pe[2][16];
#pragma unroll
        for (int kg = 0; kg < 2; ++kg)
#pragma unroll
          for (int rr = 0; rr < 16; ++rr) {
            float sv = sacc[kg][rr];
            if (need_mask) {
              const int krel = kb * 64 + kg * 32 + (rr & 3) + 8 * (rr >> 2);
              if (krel > qm) sv = NEGBIG;                   // key > q -> masked
            }
            float e;
            asm("v_exp_f32 %0, %1" : "=v"(e) : "v"(sv));    // 2^sv; 2^-1e30 = 0
            pe[kg][rr] = e;
            lsum += e;
          }
        // pack P^T to bf16, redistribute to PV A-frags (round-3/5/7-verified)
        unsigned W0[2][4], W1[2][4];
#pragma unroll
        for (int kg = 0; kg < 2; ++kg)
#pragma unroll
          for (int r4 = 0; r4 < 4; ++r4) {
            asm("v_cvt_pk_bf16_f32 %0, %1, %2"
                : "=v"(W0[kg][r4]) : "v"(pe[kg][4 * r4 + 0]), "v"(pe[kg][4 * r4 + 1]));
            asm("v_cvt_pk_bf16_f32 %0, %1, %2"
                : "=v"(W1[kg][r4]) : "v"(pe[kg][4 * r4 + 2]), "v"(pe[kg][4 * r4 + 3]));
          }
        bf16x8 pA[4];
#pragma unroll
        for (int ks = 0; ks < 4; ++ks) {
          const int kg = ks >> 1, sel = ks & 1;
          unsigned a0 = W0[kg][2 * sel], b0 = W0[kg][2 * sel + 1];
          unsigned a1 = W1[kg][2 * sel], b1 = W1[kg][2 * sel + 1];
          asm("v_permlane32_swap_b32 %0, %1" : "+v"(a0), "+v"(b0));
          asm("v_permlane32_swap_b32 %0, %1" : "+v"(a1), "+v"(b1));
          unsigned wds[4] = {a0, a1, b0, b1};               // keys e01,e23,e45,e67
          pA[ks] = *(const bf16x8*)wds;
        }
        // PV(kb) SAME slot (TLP from 4 waves/SIMD hides the serial chain)
#pragma unroll
        for (int dg = 0; dg < 2; ++dg)
#pragma unroll
          for (int ks = 0; ks < 4; ++ks) {
            bf16x8 vf = *(const bf16x8*)&vt0[ck * 4608 + (dg * 32 + c) * 72 + ks * 16 + h2 * 8];
            oacc[dg] = __builtin_amdgcn_mfma_f32_32x32x16_bf16(pA[ks], vf, oacc[dg], 0, 0, 0);
          }
      }
      if (pref) {                                           // write kb+4 -> other buf
#pragma unroll
        for (int r = 0; r < 2; ++r) {
          const int si = si0 + 32 * r;
          *(short8*)&kt0[(1 - ck) * 4608 + si * 72 + so] = pk[r];
          *(short8*)&vt0[(1 - ck) * 4608 + si * 72 + so] = pv[r];
        }
      }
      __syncthreads();                                      // one barrier per slot
    }
    // ---- 4-way merge via overlay on dead kt/vt (loop's last barrier fences reads) ----
    lsum += __shfl_xor(lsum, 32);                           // l partial for q=c
    if (grp != 0) {
      const int base = ((grp - 1) * 4 + wg) * 2048;
#pragma unroll
      for (int dg = 0; dg < 2; ++dg)
#pragma unroll
        for (int rr = 0; rr < 16; ++rr)
          Ms[base + (dg * 16 + rr) * 64 + l] = oacc[dg][rr];
      Lxp[((grp - 1) * 4 + wg) * 64 + l] = lsum;
    }
    __syncthreads();
    if (grp == 0) {
      float lt = lsum;
#pragma unroll
      for (int g = 1; g < 4; ++g) lt += Lxp[((g - 1) * 4 + wg) * 64 + l];
      const float inv = 1.0f / lt;                          // valid for q=c
#pragma unroll
      for (int dg = 0; dg < 2; ++dg)
#pragma unroll
        for (int rr = 0; rr < 16; ++rr) {
          float o = oacc[dg][rr];
#pragma unroll
          for (int g = 1; g < 4; ++g)
            o += Ms[((g - 1) * 4 + wg) * 2048 + (dg * 16 + rr) * 64 + l];
          oacc[dg][rr] = o;
        }
#pragma unroll
      for (int rr = 0; rr < 16; ++rr) {
        const int q_rel = (rr & 3) + 8 * (rr >> 2) + 4 * h2;
        const float iq = __shfl(inv, q_rel);
        const size_t trow = qbase + q_rel;
#pragma unroll
        for (int dg = 0; dg < 2; ++dg)
          Qp[trow * 2048 + dg * 32 + c] = f2bf(oacc[dg][rr] * iq);
      }
    }
  }
}

extern "C" void kernel_launch(void* const* d_in, const int* in_sizes, int n_in,
                              void* d_out, int out_size, void* d_ws, size_t ws_size,
                              hipStream_t stream)
{
  (void)in_sizes; (void)n_in; (void)out_size; (void)ws_size;
  const float* x     = (const float*)d_in[0];   // [B,T,C] fp32
  const float* Wqkv  = (const float*)d_in[1];   // [C,3C]
  const float* bqkv  = (const float*)d_in[2];   // [3C]
  const float* Wproj = (const float*)d_in[3];   // [C,C]
  const float* bproj = (const float*)d_in[4];   // [C]

  unsigned short* QK     = (unsigned short*)d_ws;            // [4096][2048] bf16, 16 MB
  unsigned short* WqkvT  = QK + (size_t)4096 * 2048;         // [3072][1024] bf16, 6 MB
  unsigned short* WprojT = WqkvT;                            // aliases (after GEMM1)
  unsigned short* Vt = (unsigned short*)d_out;               // scratch in d_out, 8 MB
  unsigned short* xb = Vt + (size_t)32 * 64 * 2048;          // scratch in d_out, 8 MB

  cvt_bf16<<<dim3(4096 * 1024 / 8 / 256), 256, 0, stream>>>(x, xb, 4096 * 1024 / 8);
  transpose_cvt<<<dim3(C3 / 64, CC / 64), 256, 0, stream>>>(Wqkv, WqkvT, CC, C3);
  gemm_bt<0><<<dim3(C3 / 128, 4096 / 128), 256, 0, stream>>>(
      xb, WqkvT, bqkv, QK, Vt, 4096, C3, CC, CC);
  transpose_cvt<<<dim3(CC / 64, CC / 64), 256, 0, stream>>>(Wproj, WprojT, CC, CC);
  attn4g<<<dim3(8, 2 * HH), 1024, 0, stream>>>(QK, Vt);
  gemm_n64<<<dim3(CC / 64, 4096 / 128), 256, 0, stream>>>(
      QK, WprojT, bproj, (float*)d_out, 4096, CC, CC, 2048);
}

// Round 12
// 180.546 us; speedup vs baseline: 1.1254x; 1.1254x over previous
//
#include <hip/hip_runtime.h>
#include <hip/hip_bf16.h>

typedef __attribute__((ext_vector_type(8))) __bf16 bf16x8;
typedef __attribute__((ext_vector_type(8))) short short8;
typedef __attribute__((ext_vector_type(4))) float f32x4;
typedef __attribute__((ext_vector_type(16))) float f32x16;
typedef __attribute__((ext_vector_type(4))) short sh4;

typedef __attribute__((address_space(1))) void GVoid;
typedef __attribute__((address_space(3))) void LVoid;

#define NEGBIG (-1e30f)
#define SCL 0.18033688011112042f   // 0.125 * log2(e): folded into Q at GEMM1 epilogue

constexpr int TT = 2048, CC = 1024, HH = 16, DD = 64, C3 = 3072;

__device__ __forceinline__ unsigned short f2bf(float f) {   // RNE
  unsigned int i = __float_as_uint(f);
  return (unsigned short)((i + 0x7FFFu + ((i >> 16) & 1u)) >> 16);
}
__device__ __forceinline__ void async16(const void* g, void* l) {
  __builtin_amdgcn_global_load_lds((GVoid*)g, (LVoid*)l, 16, 0, 0);
}

// ---------- pre-pass: fp32 -> bf16 elementwise convert ----------
__global__ __launch_bounds__(256) void cvt_bf16(
    const float* __restrict__ in, unsigned short* __restrict__ out, int n8)
{
  const int i = blockIdx.x * 256 + threadIdx.x;
  if (i >= n8) return;
  const float* p = in + (size_t)i * 8;
  f32x4 a = *(const f32x4*)p, b = *(const f32x4*)(p + 4);
  sh4 r0, r1;
  ((unsigned short*)&r0)[0] = f2bf(a[0]); ((unsigned short*)&r0)[1] = f2bf(a[1]);
  ((unsigned short*)&r0)[2] = f2bf(a[2]); ((unsigned short*)&r0)[3] = f2bf(a[3]);
  ((unsigned short*)&r1)[0] = f2bf(b[0]); ((unsigned short*)&r1)[1] = f2bf(b[1]);
  ((unsigned short*)&r1)[2] = f2bf(b[2]); ((unsigned short*)&r1)[3] = f2bf(b[3]);
  *(sh4*)(out + (size_t)i * 8) = r0;
  *(sh4*)(out + (size_t)i * 8 + 4) = r1;
}

// ---------- pre-pass: transpose + convert: fp32 in[R][Cd] -> bf16 out[Cd][R] ----------
__global__ __launch_bounds__(256) void transpose_cvt(
    const float* __restrict__ in, unsigned short* __restrict__ out, int R, int Cd)
{
  __shared__ __align__(16) unsigned short tile[64 * 72];
  const int r0 = blockIdx.y * 64, c0 = blockIdx.x * 64;
  const int tid = threadIdx.x;
#pragma unroll
  for (int r = 0; r < 2; ++r) {
    const int elem = r * 2048 + tid * 8;
    const int ii = elem >> 6, jj = elem & 63;
    const float* p = in + (size_t)(r0 + ii) * Cd + c0 + jj;
    f32x4 a = *(const f32x4*)p, b = *(const f32x4*)(p + 4);
    short8 v;
    ((unsigned short*)&v)[0] = f2bf(a[0]); ((unsigned short*)&v)[1] = f2bf(a[1]);
    ((unsigned short*)&v)[2] = f2bf(a[2]); ((unsigned short*)&v)[3] = f2bf(a[3]);
    ((unsigned short*)&v)[4] = f2bf(b[0]); ((unsigned short*)&v)[5] = f2bf(b[1]);
    ((unsigned short*)&v)[6] = f2bf(b[2]); ((unsigned short*)&v)[7] = f2bf(b[3]);
    *(short8*)&tile[ii * 72 + jj] = v;
  }
  __syncthreads();
#pragma unroll
  for (int r = 0; r < 2; ++r) {
    const int elem = r * 2048 + tid * 8;
    const int jj = elem >> 6, ii0 = elem & 63;
    short8 v;
#pragma unroll
    for (int e = 0; e < 8; ++e) ((unsigned short*)&v)[e] = tile[(ii0 + e) * 72 + jj];
    *(short8*)&out[(size_t)(c0 + jj) * R + r0 + ii0] = v;
  }
}

// ---------------- GEMM, 128x128 tile, single-barrier double-buffered ----------------
// (round-8 best-measured version; XCD swizzle tried r11 was neutral-to-negative
// with L3-fit data and is reverted.)
// MODE 0 (QKV): gn<1024 -> Q*SCL bf16; 1024..2047 -> K bf16; >=2048 -> Vt packed.
template <int MODE>
__global__ __launch_bounds__(256) void gemm_bt(
    const unsigned short* __restrict__ A,
    const unsigned short* __restrict__ Bt,
    const float* __restrict__ bias,
    void* __restrict__ Cp, unsigned short* __restrict__ Vt,
    int M, int N, int K, int lda)
{
  __shared__ __align__(16) unsigned short sA[2][128 * 32];
  __shared__ __align__(16) unsigned short sB[2][128 * 32];
  const int tid = threadIdx.x;
  const int w = tid >> 6, l = tid & 63, ln = l & 15, quad = l >> 4;
  const int wm = w >> 1, wn = w & 1;
  const int m0 = blockIdx.y * 128, n0 = blockIdx.x * 128;
  f32x4 acc[4][4] = {};

  const int elem0 = tid * 8;                 // staging coords (constant per thread)
  const int ar0 = elem0 >> 5, ac0 = elem0 & 31;
  const int ar1 = (2048 + elem0) >> 5, ac1 = ac0;

  // prologue: stage k0=0 into buf 0
  async16(A  + (size_t)(m0 + ar0) * lda + ac0, &sA[0][w * 512]);
  async16(Bt + (size_t)(n0 + ar0) * K   + ac0, &sB[0][w * 512]);
  async16(A  + (size_t)(m0 + ar1) * lda + ac1, &sA[0][2048 + w * 512]);
  async16(Bt + (size_t)(n0 + ar1) * K   + ac1, &sB[0][2048 + w * 512]);
  __syncthreads();                           // implicit vmcnt(0) drain: buf0 ready

  int buf = 0;
  for (int k0 = 0; k0 < K; k0 += 32, buf ^= 1) {
    if (k0 + 32 < K) {                       // stage NEXT tile into other buffer
      const int nb = buf ^ 1, kn = k0 + 32;
      async16(A  + (size_t)(m0 + ar0) * lda + kn + ac0, &sA[nb][w * 512]);
      async16(Bt + (size_t)(n0 + ar0) * K   + kn + ac0, &sB[nb][w * 512]);
      async16(A  + (size_t)(m0 + ar1) * lda + kn + ac1, &sA[nb][2048 + w * 512]);
      async16(Bt + (size_t)(n0 + ar1) * K   + kn + ac1, &sB[nb][2048 + w * 512]);
    }

    bf16x8 af[4], bfr[4];
#pragma unroll
    for (int i = 0; i < 4; i++)
      af[i] = *(const bf16x8*)&sA[buf][(wm * 64 + i * 16 + ln) * 32 + quad * 8];
#pragma unroll
    for (int j = 0; j < 4; j++)
      bfr[j] = *(const bf16x8*)&sB[buf][(wn * 64 + j * 16 + ln) * 32 + quad * 8];
#pragma unroll
    for (int i = 0; i < 4; i++)
#pragma unroll
      for (int j = 0; j < 4; j++)
        acc[i][j] = __builtin_amdgcn_mfma_f32_16x16x32_bf16(af[i], bfr[j], acc[i][j], 0, 0, 0);

    __syncthreads();                         // one barrier/K-step
  }

  float bj[4];
#pragma unroll
  for (int j = 0; j < 4; j++) bj[j] = bias[n0 + wn * 64 + j * 16 + ln];

#pragma unroll
  for (int i = 0; i < 4; i++) {
#pragma unroll
    for (int j = 0; j < 4; j++) {
      const int gn = n0 + wn * 64 + j * 16 + ln;
      if (MODE == 0 && gn >= 2048) {                 // V: pack g-quad -> one 8B store
        const int hh = (gn >> 6) & 15, dd = gn & 63;
        const int gm0 = m0 + wm * 64 + i * 16 + quad * 4;
        const int bb = gm0 >> 11, t0 = gm0 & 2047;   // g-quad never crosses batch
        sh4 rv;
#pragma unroll
        for (int g = 0; g < 4; ++g)
          ((unsigned short*)&rv)[g] = f2bf(acc[i][j][g] + bj[j]);
        *(sh4*)&Vt[((size_t)((bb * HH + hh) * DD + dd)) * TT + t0] = rv;
      } else {
#pragma unroll
        for (int g = 0; g < 4; ++g) {
          const int gm = m0 + wm * 64 + i * 16 + quad * 4 + g;
          float v = acc[i][j][g] + bj[j];
          if (MODE == 0) {
            if (gn < 1024) v *= SCL;   // fold softmax scale into Q (pre-round: free)
            ((unsigned short*)Cp)[(size_t)gm * 2048 + gn] = f2bf(v);
          } else {
            ((float*)Cp)[(size_t)gm * N + gn] = v;
          }
        }
      }
    }
  }
}

// ---------------- GEMM, 128x64 tile (proj: 512 blocks = 2/CU), same pipeline ----------------
__global__ __launch_bounds__(256) void gemm_n64(
    const unsigned short* __restrict__ A,
    const unsigned short* __restrict__ Bt,
    const float* __restrict__ bias,
    float* __restrict__ Cp, int M, int N, int K, int lda)
{
  __shared__ __align__(16) unsigned short sA[2][128 * 32];
  __shared__ __align__(16) unsigned short sB[2][64 * 32];
  const int tid = threadIdx.x;
  const int w = tid >> 6, l = tid & 63, ln = l & 15, quad = l >> 4;
  const int wm = w >> 1, wn = w & 1;
  const int m0 = blockIdx.y * 128, n0 = blockIdx.x * 64;
  f32x4 acc[4][2] = {};

  const int elem0 = tid * 8;
  const int ar0 = elem0 >> 5, ac0 = elem0 & 31;
  const int ar1 = (2048 + elem0) >> 5, ac1 = ac0;

  async16(A  + (size_t)(m0 + ar0) * lda + ac0, &sA[0][w * 512]);
  async16(A  + (size_t)(m0 + ar1) * lda + ac1, &sA[0][2048 + w * 512]);
  async16(Bt + (size_t)(n0 + ar0) * K   + ac0, &sB[0][w * 512]);
  __syncthreads();

  int buf = 0;
  for (int k0 = 0; k0 < K; k0 += 32, buf ^= 1) {
    if (k0 + 32 < K) {
      const int nb = buf ^ 1, kn = k0 + 32;
      async16(A  + (size_t)(m0 + ar0) * lda + kn + ac0, &sA[nb][w * 512]);
      async16(A  + (size_t)(m0 + ar1) * lda + kn + ac1, &sA[nb][2048 + w * 512]);
      async16(Bt + (size_t)(n0 + ar0) * K   + kn + ac0, &sB[nb][w * 512]);
    }

    bf16x8 af[4], bfr[2];
#pragma unroll
    for (int i = 0; i < 4; i++)
      af[i] = *(const bf16x8*)&sA[buf][(wm * 64 + i * 16 + ln) * 32 + quad * 8];
#pragma unroll
    for (int j = 0; j < 2; j++)
      bfr[j] = *(const bf16x8*)&sB[buf][(wn * 32 + j * 16 + ln) * 32 + quad * 8];
#pragma unroll
    for (int i = 0; i < 4; i++)
#pragma unroll
      for (int j = 0; j < 2; j++)
        acc[i][j] = __builtin_amdgcn_mfma_f32_16x16x32_bf16(af[i], bfr[j], acc[i][j], 0, 0, 0);

    __syncthreads();
  }

  float bj[2];
#pragma unroll
  for (int j = 0; j < 2; j++) bj[j] = bias[n0 + wn * 32 + j * 16 + ln];

#pragma unroll
  for (int i = 0; i < 4; i++)
#pragma unroll
    for (int g = 0; g < 4; ++g) {
      const int gm = m0 + wm * 64 + i * 16 + quad * 4 + g;
#pragma unroll
      for (int j = 0; j < 2; j++) {
        const int gn = n0 + wn * 32 + j * 16 + ln;
        Cp[(size_t)gm * N + gn] = acc[i][j][g] + bj[j];
      }
    }
}

// ---------------- Flash attention (causal), D=64, 2 parity groups ----------------
// Round-7/8 best-measured structure (attn2g ~43us) + two additions:
//  * bh->XCD AFFINITY remap: old grid (pair fast) spread the 8 pair-blocks of one
//    bh across 8 XCDs -> each XCD's L2 separately refilled that bh's K/V (512KB)
//    from L3 -> ~8x K/V broadcast waste (measured 70MB FETCH vs ~24MB ideal).
//    Remap (bijective): xcd=lid&7 owns bh {4*xcd..4*xcd+3} x all 8 pairs -> per-XCD
//    K/V working set 2MB < 4MB L2 -> L3/HBM misses become L2 hits.
//  * s_setprio(1) around QK and PV MFMA clusters (T5: parity groups give the wave
//    role diversity setprio needs; guide: +4-7% attn).
__global__ __launch_bounds__(512) void attn2g(
    unsigned short* __restrict__ QK, const unsigned short* __restrict__ Vt)
{
  __shared__ __align__(16) unsigned short kt[2][2][64 * 72];  // [grp][buf][key][d]
  __shared__ __align__(16) unsigned short vt[2][3][64 * 72];  // [grp][buf][d][key]
  __shared__ float Ox[4][2][16][64];                          // [wg][dg][rr][lane]
  __shared__ float Lx[4][64];
  // bh->XCD affinity (workgroup->XCD is round-robin on dispatch index)
  const int lid = blockIdx.y * gridDim.x + blockIdx.x;        // 0..255
  const int xcd = lid & 7, idx = lid >> 3;
  const int bh = xcd * 4 + (idx & 3);                         // 4 bh per XCD
  const int pair = idx >> 2;                                  // 0..7
  const int b = bh >> 4, h = bh & 15;
  const int tid = threadIdx.x;
  const int grp = tid >> 8, gtid = tid & 255;                 // waves 0-3 / 4-7
  const int wg = (tid >> 6) & 3, l = tid & 63;
  const int c = l & 31, h2 = l >> 5;
  unsigned short*       Qp = QK + (size_t)b * TT * 2048 + h * DD;
  const unsigned short* Kp = QK + (size_t)b * TT * 2048 + CC + h * DD;
  const unsigned short* Vh = Vt + (size_t)bh * DD * TT;
  const int si0 = gtid >> 3, so = (gtid & 7) * 8;             // group stages 64x64

  for (int ph = 0; ph < 2; ++ph) {
    const int qt = ph ? 15 - pair : pair;
    const int qbase = qt * 128 + wg * 32;                     // wave's first q-row
    const int qm = qbase + c - 4 * h2;                        // mask helper (verified)
    bf16x8 qv[4];
#pragma unroll
    for (int ds = 0; ds < 4; ++ds)                            // Q B-operand frags
      qv[ds] = *(const bf16x8*)&Qp[(size_t)(qbase + c) * 2048 + ds * 16 + h2 * 8];

    f32x16 oacc[2] = {};
    bf16x8 pA[4] = {};
    float lsum = 0.0f;
    const int nslot = qt + 1;                                 // tiles per group
    int vm1 = 2, v0 = 0, vp1 = 1;

    __syncthreads();                                          // prior phase done
#pragma unroll
    for (int r = 0; r < 2; ++r) {                             // stage kb=grp -> buf 0
      const int si = si0 + 32 * r;
      *(short8*)&kt[grp][0][si * 72 + so] =
          *(const short8*)&Kp[(size_t)(grp * 64 + si) * 2048 + so];
      *(short8*)&vt[grp][0][si * 72 + so] =
          *(const short8*)&Vh[(size_t)si * TT + grp * 64 + so];
    }
    __syncthreads();                                          // buf0 visible

    for (int slot = 0; slot < nslot; ++slot) {
      const int kb = 2 * slot + grp;                          // this group's tile
      const int ck = slot & 1;
      short8 pk[2], pv[2];
      if (slot + 1 < nslot) {                                 // prefetch kb+2 -> regs
        const int kbn = kb + 2;
#pragma unroll
        for (int r = 0; r < 2; ++r) {
          const int si = si0 + 32 * r;
          pk[r] = *(const short8*)&Kp[(size_t)(kbn * 64 + si) * 2048 + so];
          pv[r] = *(const short8*)&Vh[(size_t)si * TT + kbn * 64 + so];
        }
      }
      const bool qk_act = (kb * 64 <= qbase + 31);            // wave-uniform
      f32x16 sacc[2];
      if (qk_act) {                                           // S^T(kb) = K * Q^T
        __builtin_amdgcn_s_setprio(1);
#pragma unroll
        for (int kg = 0; kg < 2; ++kg) {
          f32x16 sa = {};
#pragma unroll
          for (int ds = 0; ds < 4; ++ds) {
            bf16x8 kf = *(const bf16x8*)&kt[grp][ck][(kg * 32 + c) * 72 + ds * 16 + h2 * 8];
            sa = __builtin_amdgcn_mfma_f32_32x32x16_bf16(kf, qv[ds], sa, 0, 0, 0);
          }
          sacc[kg] = sa;
        }
        __builtin_amdgcn_s_setprio(0);
      }
      if (slot > 0 && (kb - 2) * 64 <= qbase + 31) {          // PV(kb-2), overlaps SM
        const unsigned short* vp = vt[grp][vm1];
        __builtin_amdgcn_s_setprio(1);
#pragma unroll
        for (int dg = 0; dg < 2; ++dg)
#pragma unroll
          for (int ks = 0; ks < 4; ++ks) {
            bf16x8 vf = *(const bf16x8*)&vp[(dg * 32 + c) * 72 + ks * 16 + h2 * 8];
            oacc[dg] = __builtin_amdgcn_mfma_f32_32x32x16_bf16(pA[ks], vf, oacc[dg], 0, 0, 0);
          }
        __builtin_amdgcn_s_setprio(0);
      }
      if (qk_act) {
        const bool need_mask = (kb * 64 + 63 > qbase);        // diagonal tiles only
        float pe[2][16];
#pragma unroll
        for (int kg = 0; kg < 2; ++kg)
#pragma unroll
          for (int rr = 0; rr < 16; ++rr) {
            float sv = sacc[kg][rr];
            if (need_mask) {
              const int krel = kb * 64 + kg * 32 + (rr & 3) + 8 * (rr >> 2);
              if (krel > qm) sv = NEGBIG;                     // key > q -> masked
            }
            float e;
            asm("v_exp_f32 %0, %1" : "=v"(e) : "v"(sv));      // 2^sv; 2^-1e30 = 0
            pe[kg][rr] = e;
            lsum += e;
          }
        // pack P^T pairs to bf16, redistribute to PV A-frags (round-3/4-verified)
        unsigned W0[2][4], W1[2][4];
#pragma unroll
        for (int kg = 0; kg < 2; ++kg)
#pragma unroll
          for (int r4 = 0; r4 < 4; ++r4) {
            asm("v_cvt_pk_bf16_f32 %0, %1, %2"
                : "=v"(W0[kg][r4]) : "v"(pe[kg][4 * r4 + 0]), "v"(pe[kg][4 * r4 + 1]));
            asm("v_cvt_pk_bf16_f32 %0, %1, %2"
                : "=v"(W1[kg][r4]) : "v"(pe[kg][4 * r4 + 2]), "v"(pe[kg][4 * r4 + 3]));
          }
#pragma unroll
        for (int ks = 0; ks < 4; ++ks) {
          const int kg = ks >> 1, sel = ks & 1;
          unsigned a0 = W0[kg][2 * sel], b0 = W0[kg][2 * sel + 1];
          unsigned a1 = W1[kg][2 * sel], b1 = W1[kg][2 * sel + 1];
          asm("v_permlane32_swap_b32 %0, %1" : "+v"(a0), "+v"(b0));
          asm("v_permlane32_swap_b32 %0, %1" : "+v"(a1), "+v"(b1));
          unsigned wds[4] = {a0, a1, b0, b1};                 // keys e01,e23,e45,e67
          pA[ks] = *(const bf16x8*)wds;
        }
      }
      if (slot + 1 < nslot) {                                 // stage kb+2
#pragma unroll
        for (int r = 0; r < 2; ++r) {
          const int si = si0 + 32 * r;
          *(short8*)&kt[grp][1 - ck][si * 72 + so] = pk[r];
          *(short8*)&vt[grp][vp1][si * 72 + so] = pv[r];
        }
      }
      __syncthreads();                                        // one barrier per slot
      const int t_ = vm1; vm1 = v0; v0 = vp1; vp1 = t_;       // rotate V buffers
    }
    // drain: PV of this group's last tile (vm1 == its V after final rotation)
    const int kb_last = 2 * qt + grp;
    if (kb_last * 64 <= qbase + 31) {
      const unsigned short* vp = vt[grp][vm1];
#pragma unroll
      for (int dg = 0; dg < 2; ++dg)
#pragma unroll
        for (int ks = 0; ks < 4; ++ks) {
          bf16x8 vf = *(const bf16x8*)&vp[(dg * 32 + c) * 72 + ks * 16 + h2 * 8];
          oacc[dg] = __builtin_amdgcn_mfma_f32_32x32x16_bf16(pA[ks], vf, oacc[dg], 0, 0, 0);
        }
    }
    // ---- merge the two parity groups (additive partials), normalize, store ----
    lsum += __shfl_xor(lsum, 32);                             // l partial for q=c
    if (grp == 1) {
#pragma unroll
      for (int dg = 0; dg < 2; ++dg)
#pragma unroll
        for (int rr = 0; rr < 16; ++rr) Ox[wg][dg][rr][l] = oacc[dg][rr];
      Lx[wg][l] = lsum;
    }
    __syncthreads();
    if (grp == 0) {
      const float inv = 1.0f / (lsum + Lx[wg][l]);            // valid for q=c
#pragma unroll
      for (int dg = 0; dg < 2; ++dg)
#pragma unroll
        for (int rr = 0; rr < 16; ++rr) oacc[dg][rr] += Ox[wg][dg][rr][l];
#pragma unroll
      for (int rr = 0; rr < 16; ++rr) {
        const int q_rel = (rr & 3) + 8 * (rr >> 2) + 4 * h2;
        const float iq = __shfl(inv, q_rel);
        const size_t trow = qbase + q_rel;
#pragma unroll
        for (int dg = 0; dg < 2; ++dg)
          Qp[trow * 2048 + dg * 32 + c] = f2bf(oacc[dg][rr] * iq);
      }
    }
  }
}

extern "C" void kernel_launch(void* const* d_in, const int* in_sizes, int n_in,
                              void* d_out, int out_size, void* d_ws, size_t ws_size,
                              hipStream_t stream)
{
  (void)in_sizes; (void)n_in; (void)out_size; (void)ws_size;
  const float* x     = (const float*)d_in[0];   // [B,T,C] fp32
  const float* Wqkv  = (const float*)d_in[1];   // [C,3C]
  const float* bqkv  = (const float*)d_in[2];   // [3C]
  const float* Wproj = (const float*)d_in[3];   // [C,C]
  const float* bproj = (const float*)d_in[4];   // [C]

  unsigned short* QK     = (unsigned short*)d_ws;            // [4096][2048] bf16, 16 MB
  unsigned short* WqkvT  = QK + (size_t)4096 * 2048;         // [3072][1024] bf16, 6 MB
  unsigned short* WprojT = WqkvT;                            // aliases (after GEMM1)
  unsigned short* Vt = (unsigned short*)d_out;               // scratch in d_out, 8 MB
  unsigned short* xb = Vt + (size_t)32 * 64 * 2048;          // scratch in d_out, 8 MB

  cvt_bf16<<<dim3(4096 * 1024 / 8 / 256), 256, 0, stream>>>(x, xb, 4096 * 1024 / 8);
  transpose_cvt<<<dim3(C3 / 64, CC / 64), 256, 0, stream>>>(Wqkv, WqkvT, CC, C3);
  gemm_bt<0><<<dim3(C3 / 128, 4096 / 128), 256, 0, stream>>>(
      xb, WqkvT, bqkv, QK, Vt, 4096, C3, CC, CC);
  transpose_cvt<<<dim3(CC / 64, CC / 64), 256, 0, stream>>>(Wproj, WprojT, CC, CC);
  attn2g<<<dim3(8, 2 * HH), 512, 0, stream>>>(QK, Vt);
  gemm_n64<<<dim3(CC / 64, 4096 / 128), 256, 0, stream>>>(
      QK, WprojT, bproj, (float*)d_out, 4096, CC, CC, 2048);
}

// Round 13
// 177.277 us; speedup vs baseline: 1.1461x; 1.0184x over previous
//
#include <hip/hip_runtime.h>
#include <hip/hip_bf16.h>

typedef __attribute__((ext_vector_type(8))) __bf16 bf16x8;
typedef __attribute__((ext_vector_type(8))) short short8;
typedef __attribute__((ext_vector_type(4))) float f32x4;
typedef __attribute__((ext_vector_type(16))) float f32x16;
typedef __attribute__((ext_vector_type(4))) short sh4;

typedef __attribute__((address_space(1))) void GVoid;
typedef __attribute__((address_space(3))) void LVoid;

#define NEGBIG (-1e30f)
#define SCL 0.18033688011112042f   // 0.125 * log2(e): folded into Q at GEMM1 epilogue

constexpr int TT = 2048, CC = 1024, HH = 16, DD = 64, C3 = 3072;

__device__ __forceinline__ unsigned short f2bf(float f) {   // RNE
  unsigned int i = __float_as_uint(f);
  return (unsigned short)((i + 0x7FFFu + ((i >> 16) & 1u)) >> 16);
}
__device__ __forceinline__ void async16(const void* g, void* l) {
  __builtin_amdgcn_global_load_lds((GVoid*)g, (LVoid*)l, 16, 0, 0);
}

// ---------- pre-pass: fp32 -> bf16 elementwise convert ----------
__global__ __launch_bounds__(256) void cvt_bf16(
    const float* __restrict__ in, unsigned short* __restrict__ out, int n8)
{
  const int i = blockIdx.x * 256 + threadIdx.x;
  if (i >= n8) return;
  const float* p = in + (size_t)i * 8;
  f32x4 a = *(const f32x4*)p, b = *(const f32x4*)(p + 4);
  sh4 r0, r1;
  ((unsigned short*)&r0)[0] = f2bf(a[0]); ((unsigned short*)&r0)[1] = f2bf(a[1]);
  ((unsigned short*)&r0)[2] = f2bf(a[2]); ((unsigned short*)&r0)[3] = f2bf(a[3]);
  ((unsigned short*)&r1)[0] = f2bf(b[0]); ((unsigned short*)&r1)[1] = f2bf(b[1]);
  ((unsigned short*)&r1)[2] = f2bf(b[2]); ((unsigned short*)&r1)[3] = f2bf(b[3]);
  *(sh4*)(out + (size_t)i * 8) = r0;
  *(sh4*)(out + (size_t)i * 8 + 4) = r1;
}

// ---------- pre-pass: transpose + convert: fp32 in[R][Cd] -> bf16 out[Cd][R] ----------
__global__ __launch_bounds__(256) void transpose_cvt(
    const float* __restrict__ in, unsigned short* __restrict__ out, int R, int Cd)
{
  __shared__ __align__(16) unsigned short tile[64 * 72];
  const int r0 = blockIdx.y * 64, c0 = blockIdx.x * 64;
  const int tid = threadIdx.x;
#pragma unroll
  for (int r = 0; r < 2; ++r) {
    const int elem = r * 2048 + tid * 8;
    const int ii = elem >> 6, jj = elem & 63;
    const float* p = in + (size_t)(r0 + ii) * Cd + c0 + jj;
    f32x4 a = *(const f32x4*)p, b = *(const f32x4*)(p + 4);
    short8 v;
    ((unsigned short*)&v)[0] = f2bf(a[0]); ((unsigned short*)&v)[1] = f2bf(a[1]);
    ((unsigned short*)&v)[2] = f2bf(a[2]); ((unsigned short*)&v)[3] = f2bf(a[3]);
    ((unsigned short*)&v)[4] = f2bf(b[0]); ((unsigned short*)&v)[5] = f2bf(b[1]);
    ((unsigned short*)&v)[6] = f2bf(b[2]); ((unsigned short*)&v)[7] = f2bf(b[3]);
    *(short8*)&tile[ii * 72 + jj] = v;
  }
  __syncthreads();
#pragma unroll
  for (int r = 0; r < 2; ++r) {
    const int elem = r * 2048 + tid * 8;
    const int jj = elem >> 6, ii0 = elem & 63;
    short8 v;
#pragma unroll
    for (int e = 0; e < 8; ++e) ((unsigned short*)&v)[e] = tile[(ii0 + e) * 72 + jj];
    *(short8*)&out[(size_t)(c0 + jj) * R + r0 + ii0] = v;
  }
}

// ---------------- GEMM, 128x128 tile, single-barrier double-buffered ----------------
// (round-8 best-measured version)
// MODE 0 (QKV): gn<1024 -> Q*SCL bf16; 1024..2047 -> K bf16; >=2048 -> Vt packed.
template <int MODE>
__global__ __launch_bounds__(256) void gemm_bt(
    const unsigned short* __restrict__ A,
    const unsigned short* __restrict__ Bt,
    const float* __restrict__ bias,
    void* __restrict__ Cp, unsigned short* __restrict__ Vt,
    int M, int N, int K, int lda)
{
  __shared__ __align__(16) unsigned short sA[2][128 * 32];
  __shared__ __align__(16) unsigned short sB[2][128 * 32];
  const int tid = threadIdx.x;
  const int w = tid >> 6, l = tid & 63, ln = l & 15, quad = l >> 4;
  const int wm = w >> 1, wn = w & 1;
  const int m0 = blockIdx.y * 128, n0 = blockIdx.x * 128;
  f32x4 acc[4][4] = {};

  const int elem0 = tid * 8;                 // staging coords (constant per thread)
  const int ar0 = elem0 >> 5, ac0 = elem0 & 31;
  const int ar1 = (2048 + elem0) >> 5, ac1 = ac0;

  // prologue: stage k0=0 into buf 0
  async16(A  + (size_t)(m0 + ar0) * lda + ac0, &sA[0][w * 512]);
  async16(Bt + (size_t)(n0 + ar0) * K   + ac0, &sB[0][w * 512]);
  async16(A  + (size_t)(m0 + ar1) * lda + ac1, &sA[0][2048 + w * 512]);
  async16(Bt + (size_t)(n0 + ar1) * K   + ac1, &sB[0][2048 + w * 512]);
  __syncthreads();                           // implicit vmcnt(0) drain: buf0 ready

  int buf = 0;
  for (int k0 = 0; k0 < K; k0 += 32, buf ^= 1) {
    if (k0 + 32 < K) {                       // stage NEXT tile into other buffer
      const int nb = buf ^ 1, kn = k0 + 32;
      async16(A  + (size_t)(m0 + ar0) * lda + kn + ac0, &sA[nb][w * 512]);
      async16(Bt + (size_t)(n0 + ar0) * K   + kn + ac0, &sB[nb][w * 512]);
      async16(A  + (size_t)(m0 + ar1) * lda + kn + ac1, &sA[nb][2048 + w * 512]);
      async16(Bt + (size_t)(n0 + ar1) * K   + kn + ac1, &sB[nb][2048 + w * 512]);
    }

    bf16x8 af[4], bfr[4];
#pragma unroll
    for (int i = 0; i < 4; i++)
      af[i] = *(const bf16x8*)&sA[buf][(wm * 64 + i * 16 + ln) * 32 + quad * 8];
#pragma unroll
    for (int j = 0; j < 4; j++)
      bfr[j] = *(const bf16x8*)&sB[buf][(wn * 64 + j * 16 + ln) * 32 + quad * 8];
#pragma unroll
    for (int i = 0; i < 4; i++)
#pragma unroll
      for (int j = 0; j < 4; j++)
        acc[i][j] = __builtin_amdgcn_mfma_f32_16x16x32_bf16(af[i], bfr[j], acc[i][j], 0, 0, 0);

    __syncthreads();                         // one barrier/K-step
  }

  float bj[4];
#pragma unroll
  for (int j = 0; j < 4; j++) bj[j] = bias[n0 + wn * 64 + j * 16 + ln];

#pragma unroll
  for (int i = 0; i < 4; i++) {
#pragma unroll
    for (int j = 0; j < 4; j++) {
      const int gn = n0 + wn * 64 + j * 16 + ln;
      if (MODE == 0 && gn >= 2048) {                 // V: pack g-quad -> one 8B store
        const int hh = (gn >> 6) & 15, dd = gn & 63;
        const int gm0 = m0 + wm * 64 + i * 16 + quad * 4;
        const int bb = gm0 >> 11, t0 = gm0 & 2047;   // g-quad never crosses batch
        sh4 rv;
#pragma unroll
        for (int g = 0; g < 4; ++g)
          ((unsigned short*)&rv)[g] = f2bf(acc[i][j][g] + bj[j]);
        *(sh4*)&Vt[((size_t)((bb * HH + hh) * DD + dd)) * TT + t0] = rv;
      } else {
#pragma unroll
        for (int g = 0; g < 4; ++g) {
          const int gm = m0 + wm * 64 + i * 16 + quad * 4 + g;
          float v = acc[i][j][g] + bj[j];
          if (MODE == 0) {
            if (gn < 1024) v *= SCL;   // fold softmax scale into Q (pre-round: free)
            ((unsigned short*)Cp)[(size_t)gm * 2048 + gn] = f2bf(v);
          } else {
            ((float*)Cp)[(size_t)gm * N + gn] = v;
          }
        }
      }
    }
  }
}

// ---------------- GEMM, 128x64 tile (proj: 512 blocks = 2/CU), same pipeline ----------------
__global__ __launch_bounds__(256) void gemm_n64(
    const unsigned short* __restrict__ A,
    const unsigned short* __restrict__ Bt,
    const float* __restrict__ bias,
    float* __restrict__ Cp, int M, int N, int K, int lda)
{
  __shared__ __align__(16) unsigned short sA[2][128 * 32];
  __shared__ __align__(16) unsigned short sB[2][64 * 32];
  const int tid = threadIdx.x;
  const int w = tid >> 6, l = tid & 63, ln = l & 15, quad = l >> 4;
  const int wm = w >> 1, wn = w & 1;
  const int m0 = blockIdx.y * 128, n0 = blockIdx.x * 64;
  f32x4 acc[4][2] = {};

  const int elem0 = tid * 8;
  const int ar0 = elem0 >> 5, ac0 = elem0 & 31;
  const int ar1 = (2048 + elem0) >> 5, ac1 = ac0;

  async16(A  + (size_t)(m0 + ar0) * lda + ac0, &sA[0][w * 512]);
  async16(A  + (size_t)(m0 + ar1) * lda + ac1, &sA[0][2048 + w * 512]);
  async16(Bt + (size_t)(n0 + ar0) * K   + ac0, &sB[0][w * 512]);
  __syncthreads();

  int buf = 0;
  for (int k0 = 0; k0 < K; k0 += 32, buf ^= 1) {
    if (k0 + 32 < K) {
      const int nb = buf ^ 1, kn = k0 + 32;
      async16(A  + (size_t)(m0 + ar0) * lda + kn + ac0, &sA[nb][w * 512]);
      async16(A  + (size_t)(m0 + ar1) * lda + kn + ac1, &sA[nb][2048 + w * 512]);
      async16(Bt + (size_t)(n0 + ar0) * K   + kn + ac0, &sB[nb][w * 512]);
    }

    bf16x8 af[4], bfr[2];
#pragma unroll
    for (int i = 0; i < 4; i++)
      af[i] = *(const bf16x8*)&sA[buf][(wm * 64 + i * 16 + ln) * 32 + quad * 8];
#pragma unroll
    for (int j = 0; j < 2; j++)
      bfr[j] = *(const bf16x8*)&sB[buf][(wn * 32 + j * 16 + ln) * 32 + quad * 8];
#pragma unroll
    for (int i = 0; i < 4; i++)
#pragma unroll
      for (int j = 0; j < 2; j++)
        acc[i][j] = __builtin_amdgcn_mfma_f32_16x16x32_bf16(af[i], bfr[j], acc[i][j], 0, 0, 0);

    __syncthreads();
  }

  float bj[2];
#pragma unroll
  for (int j = 0; j < 2; j++) bj[j] = bias[n0 + wn * 32 + j * 16 + ln];

#pragma unroll
  for (int i = 0; i < 4; i++)
#pragma unroll
    for (int g = 0; g < 4; ++g) {
      const int gm = m0 + wm * 64 + i * 16 + quad * 4 + g;
#pragma unroll
      for (int j = 0; j < 2; j++) {
        const int gn = n0 + wn * 32 + j * 16 + ln;
        Cp[(size_t)gm * N + gn] = acc[i][j][g] + bj[j];
      }
    }
}

// ---------------- Flash attention (causal), D=64, 2 parity groups ----------------
// Round-12 post-mortem: attn is per-slot-overhead bound (5.3 kcy/slot vs <2 kcy of
// computable work; traffic at 20% HBM exonerated by the r12 null). This version
// amortizes the overhead: TWO 64-key tiles per barrier (barriers 17 -> 9/block),
// 4-deep buffer rotation (tile t -> buf t&3), same-slot PV (PV-lag was neutral, r2).
// Staggered prefetch keeps peak prefetch regs at 32 and gives each load a full
// compute phase: load(t+2) -> compute(t) -> write(t+2) -> load(t+3) -> compute(t+1)
// -> write(t+3) -> barrier. All verified math (32x32 S^T MFMA, in-register
// cvt_pk/permlane32_swap softmax, raw v_exp_f32, mask/merge formulas) unchanged.
// LDS 144KB (kt 72KB + vt 72KB); O/l merge overlays dead kt space after the loop.
__global__ __launch_bounds__(512) void attn2g(
    unsigned short* __restrict__ QK, const unsigned short* __restrict__ Vt)
{
  __shared__ __align__(16) unsigned short smem[73728];        // 144 KB
  // kt(grp,buf) = smem + (grp*4+buf)*4608 ; vt(grp,buf) = smem+36864 + (grp*4+buf)*4608
  float* Ms  = (float*)smem;                                  // [wg][dg][rr][l] overlay 32KB
  float* Lxp = (float*)smem + 8192;                           // [wg][l] overlay
  const int lid = blockIdx.y * gridDim.x + blockIdx.x;        // 0..255
  const int xcd = lid & 7, idx = lid >> 3;
  const int bh = xcd * 4 + (idx & 3);                         // 4 bh per XCD (r12)
  const int pair = idx >> 2;                                  // 0..7
  const int b = bh >> 4, h = bh & 15;
  const int tid = threadIdx.x;
  const int grp = tid >> 8, gtid = tid & 255;                 // waves 0-3 / 4-7
  const int wg = (tid >> 6) & 3, l = tid & 63;
  const int c = l & 31, h2 = l >> 5;
  unsigned short*       Qp = QK + (size_t)b * TT * 2048 + h * DD;
  const unsigned short* Kp = QK + (size_t)b * TT * 2048 + CC + h * DD;
  const unsigned short* Vh = Vt + (size_t)bh * DD * TT;
  const int si0 = gtid >> 3, so = (gtid & 7) * 8;             // group stages 64x64
  unsigned short* kt0 = smem + grp * 4 * 4608;
  unsigned short* vt0 = smem + 36864 + grp * 4 * 4608;

  for (int ph = 0; ph < 2; ++ph) {
    const int qt = ph ? 15 - pair : pair;
    const int qbase = qt * 128 + wg * 32;                     // wave's first q-row
    const int qm = qbase + c - 4 * h2;                        // mask helper (verified)
    bf16x8 qv[4];
#pragma unroll
    for (int ds = 0; ds < 4; ++ds)                            // Q B-operand frags
      qv[ds] = *(const bf16x8*)&Qp[(size_t)(qbase + c) * 2048 + ds * 16 + h2 * 8];

    f32x16 oacc[2] = {};
    float lsum = 0.0f;
    const int ntile = qt + 1;                                 // 64-key tiles per group

    // verified per-tile body (QK -> static softmax -> in-reg pack -> PV same-slot)
    auto compute = [&](int t) {
      const int kb = 2 * t + grp;
      if (kb * 64 > qbase + 31) return;                       // wave-uniform
      const unsigned short* ktp = kt0 + (t & 3) * 4608;
      const unsigned short* vtp = vt0 + (t & 3) * 4608;
      f32x16 sacc[2];
      __builtin_amdgcn_s_setprio(1);
#pragma unroll
      for (int kg = 0; kg < 2; ++kg) {                        // S^T = K * Q^T
        f32x16 sa = {};
#pragma unroll
        for (int ds = 0; ds < 4; ++ds) {
          bf16x8 kf = *(const bf16x8*)&ktp[(kg * 32 + c) * 72 + ds * 16 + h2 * 8];
          sa = __builtin_amdgcn_mfma_f32_32x32x16_bf16(kf, qv[ds], sa, 0, 0, 0);
        }
        sacc[kg] = sa;
      }
      __builtin_amdgcn_s_setprio(0);
      const bool need_mask = (kb * 64 + 63 > qbase);          // diagonal tiles only
      float pe[2][16];
#pragma unroll
      for (int kg = 0; kg < 2; ++kg)
#pragma unroll
        for (int rr = 0; rr < 16; ++rr) {
          float sv = sacc[kg][rr];
          if (need_mask) {
            const int krel = kb * 64 + kg * 32 + (rr & 3) + 8 * (rr >> 2);
            if (krel > qm) sv = NEGBIG;                       // key > q -> masked
          }
          float e;
          asm("v_exp_f32 %0, %1" : "=v"(e) : "v"(sv));        // 2^sv; 2^-1e30 = 0
          pe[kg][rr] = e;
          lsum += e;
        }
      unsigned W0[2][4], W1[2][4];
#pragma unroll
      for (int kg = 0; kg < 2; ++kg)
#pragma unroll
        for (int r4 = 0; r4 < 4; ++r4) {
          asm("v_cvt_pk_bf16_f32 %0, %1, %2"
              : "=v"(W0[kg][r4]) : "v"(pe[kg][4 * r4 + 0]), "v"(pe[kg][4 * r4 + 1]));
          asm("v_cvt_pk_bf16_f32 %0, %1, %2"
              : "=v"(W1[kg][r4]) : "v"(pe[kg][4 * r4 + 2]), "v"(pe[kg][4 * r4 + 3]));
        }
      bf16x8 pA[4];
#pragma unroll
      for (int ks = 0; ks < 4; ++ks) {
        const int kg = ks >> 1, sel = ks & 1;
        unsigned a0 = W0[kg][2 * sel], b0 = W0[kg][2 * sel + 1];
        unsigned a1 = W1[kg][2 * sel], b1 = W1[kg][2 * sel + 1];
        asm("v_permlane32_swap_b32 %0, %1" : "+v"(a0), "+v"(b0));
        asm("v_permlane32_swap_b32 %0, %1" : "+v"(a1), "+v"(b1));
        unsigned wds[4] = {a0, a1, b0, b1};                   // keys e01,e23,e45,e67
        pA[ks] = *(const bf16x8*)wds;
      }
      __builtin_amdgcn_s_setprio(1);
#pragma unroll
      for (int dg = 0; dg < 2; ++dg)
#pragma unroll
        for (int ks = 0; ks < 4; ++ks) {
          bf16x8 vf = *(const bf16x8*)&vtp[(dg * 32 + c) * 72 + ks * 16 + h2 * 8];
          oacc[dg] = __builtin_amdgcn_mfma_f32_32x32x16_bf16(pA[ks], vf, oacc[dg], 0, 0, 0);
        }
      __builtin_amdgcn_s_setprio(0);
    };

    __syncthreads();                                          // prior phase merge done
    {                                                         // prologue: stage t=0 (,1)
      const int kb0 = grp;
#pragma unroll
      for (int r = 0; r < 2; ++r) {
        const int si = si0 + 32 * r;
        *(short8*)&kt0[si * 72 + so] = *(const short8*)&Kp[(size_t)(kb0 * 64 + si) * 2048 + so];
        *(short8*)&vt0[si * 72 + so] = *(const short8*)&Vh[(size_t)si * TT + kb0 * 64 + so];
      }
      if (ntile > 1) {
        const int kb1 = 2 + grp;
#pragma unroll
        for (int r = 0; r < 2; ++r) {
          const int si = si0 + 32 * r;
          *(short8*)&kt0[4608 + si * 72 + so] =
              *(const short8*)&Kp[(size_t)(kb1 * 64 + si) * 2048 + so];
          *(short8*)&vt0[4608 + si * 72 + so] =
              *(const short8*)&Vh[(size_t)si * TT + kb1 * 64 + so];
        }
      }
    }
    __syncthreads();                                          // bufs 0,1 visible

    const int S = (ntile + 1) >> 1;                           // 2 tiles per barrier
    for (int s = 0; s < S; ++s) {
      const int t2 = 2 * s + 2, t3 = 2 * s + 3;
      short8 pk[2], pv[2];
      if (t2 < ntile) {                                       // load tile t2 -> regs
        const int kb = 2 * t2 + grp;
#pragma unroll
        for (int r = 0; r < 2; ++r) {
          const int si = si0 + 32 * r;
          pk[r] = *(const short8*)&Kp[(size_t)(kb * 64 + si) * 2048 + so];
          pv[r] = *(const short8*)&Vh[(size_t)si * TT + kb * 64 + so];
        }
      }
      compute(2 * s);                                         // overlaps t2 load
      if (t2 < ntile) {                                       // write t2 -> buf t2&3
#pragma unroll
        for (int r = 0; r < 2; ++r) {
          const int si = si0 + 32 * r;
          *(short8*)&kt0[(t2 & 3) * 4608 + si * 72 + so] = pk[r];
          *(short8*)&vt0[(t2 & 3) * 4608 + si * 72 + so] = pv[r];
        }
      }
      if (t3 < ntile) {                                       // load tile t3 -> regs
        const int kb = 2 * t3 + grp;
#pragma unroll
        for (int r = 0; r < 2; ++r) {
          const int si = si0 + 32 * r;
          pk[r] = *(const short8*)&Kp[(size_t)(kb * 64 + si) * 2048 + so];
          pv[r] = *(const short8*)&Vh[(size_t)si * TT + kb * 64 + so];
        }
      }
      if (2 * s + 1 < ntile) compute(2 * s + 1);              // overlaps t3 load
      if (t3 < ntile) {                                       // write t3 -> buf t3&3
#pragma unroll
        for (int r = 0; r < 2; ++r) {
          const int si = si0 + 32 * r;
          *(short8*)&kt0[(t3 & 3) * 4608 + si * 72 + so] = pk[r];
          *(short8*)&vt0[(t3 & 3) * 4608 + si * 72 + so] = pv[r];
        }
      }
      __syncthreads();                                        // ONE barrier per 2 tiles
    }

    // ---- merge the two parity groups (additive partials), normalize, store ----
    // (overlay on dead kt space; loop's last barrier fences all kt/vt reads)
    lsum += __shfl_xor(lsum, 32);                             // l partial for q=c
    if (grp == 1) {
#pragma unroll
      for (int dg = 0; dg < 2; ++dg)
#pragma unroll
        for (int rr = 0; rr < 16; ++rr)
          Ms[((wg * 2 + dg) * 16 + rr) * 64 + l] = oacc[dg][rr];
      Lxp[wg * 64 + l] = lsum;
    }
    __syncthreads();
    if (grp == 0) {
      const float inv = 1.0f / (lsum + Lxp[wg * 64 + l]);     // valid for q=c
#pragma unroll
      for (int dg = 0; dg < 2; ++dg)
#pragma unroll
        for (int rr = 0; rr < 16; ++rr)
          oacc[dg][rr] += Ms[((wg * 2 + dg) * 16 + rr) * 64 + l];
#pragma unroll
      for (int rr = 0; rr < 16; ++rr) {
        const int q_rel = (rr & 3) + 8 * (rr >> 2) + 4 * h2;
        const float iq = __shfl(inv, q_rel);
        const size_t trow = qbase + q_rel;
#pragma unroll
        for (int dg = 0; dg < 2; ++dg)
          Qp[trow * 2048 + dg * 32 + c] = f2bf(oacc[dg][rr] * iq);
      }
    }
  }
}

extern "C" void kernel_launch(void* const* d_in, const int* in_sizes, int n_in,
                              void* d_out, int out_size, void* d_ws, size_t ws_size,
                              hipStream_t stream)
{
  (void)in_sizes; (void)n_in; (void)out_size; (void)ws_size;
  const float* x     = (const float*)d_in[0];   // [B,T,C] fp32
  const float* Wqkv  = (const float*)d_in[1];   // [C,3C]
  const float* bqkv  = (const float*)d_in[2];   // [3C]
  const float* Wproj = (const float*)d_in[3];   // [C,C]
  const float* bproj = (const float*)d_in[4];   // [C]

  unsigned short* QK     = (unsigned short*)d_ws;            // [4096][2048] bf16, 16 MB
  unsigned short* WqkvT  = QK + (size_t)4096 * 2048;         // [3072][1024] bf16, 6 MB
  unsigned short* WprojT = WqkvT;                            // aliases (after GEMM1)
  unsigned short* Vt = (unsigned short*)d_out;               // scratch in d_out, 8 MB
  unsigned short* xb = Vt + (size_t)32 * 64 * 2048;          // scratch in d_out, 8 MB

  cvt_bf16<<<dim3(4096 * 1024 / 8 / 256), 256, 0, stream>>>(x, xb, 4096 * 1024 / 8);
  transpose_cvt<<<dim3(C3 / 64, CC / 64), 256, 0, stream>>>(Wqkv, WqkvT, CC, C3);
  gemm_bt<0><<<dim3(C3 / 128, 4096 / 128), 256, 0, stream>>>(
      xb, WqkvT, bqkv, QK, Vt, 4096, C3, CC, CC);
  transpose_cvt<<<dim3(CC / 64, CC / 64), 256, 0, stream>>>(Wproj, WprojT, CC, CC);
  attn2g<<<dim3(8, 2 * HH), 512, 0, stream>>>(QK, Vt);
  gemm_n64<<<dim3(CC / 64, 4096 / 128), 256, 0, stream>>>(
      QK, WprojT, bproj, (float*)d_out, 4096, CC, CC, 2048);
}